// Round 4
// baseline (121.329 us; speedup 1.0000x reference)
//
#include <hip/hip_runtime.h>
#include <hip/hip_bf16.h>
#include <stdint.h>

#define N_PTS   4096
#define M_CODES 4096
#define ZDIM    1024
// fp8 tiled layout: elem (r,k) at seg(rb)*16384 + kg*128 + r16*8 + ke  (BYTES)
//   rb=r>>4, r16=r&15, kg=k>>3, ke=k&7. Chunk (rb,kg) = 16 rows x 8 k = 128 B.
//   Seg = 16 rows x 1024 k x 1 B = 16 KB.

typedef __attribute__((ext_vector_type(4))) float f32x4;
typedef __attribute__((ext_vector_type(8))) int   i32x8;

__device__ __forceinline__ unsigned enc_f32(float f) {
    unsigned u = __float_as_uint(f);
    return (u & 0x80000000u) ? ~u : (u | 0x80000000u);
}
__device__ __forceinline__ float dec_f32(unsigned e) {
    unsigned u = (e & 0x80000000u) ? (e ^ 0x80000000u) : ~e;
    return __uint_as_float(u);
}

// ---------------------------------------------------------------------------
// prep: fp32 -> fp8 e4m3 (OCP) + tiled layout + row sum-of-squares (fp32,
// pre-quantization — error enters as 2(e.dz+z.de), sigma~2 << 35.5 threshold).
// One block = 16 rows. grid 512 (256 z + 256 e).
// ---------------------------------------------------------------------------
#define PREP_PITCH_B 1040   // bytes per LDS row: 1024 + 16 pad
__global__ __launch_bounds__(256) void prep_kernel(
    const float* __restrict__ z, const float* __restrict__ e,
    uint8_t* __restrict__ zb, uint8_t* __restrict__ eb,
    float* __restrict__ zsq, float* __restrict__ esq,
    unsigned* __restrict__ min_enc) {
    __shared__ uint8_t tile[16 * PREP_PITCH_B];   // ~16.6 KB
    __shared__ float redbuf[16 * 4];

    const int t = threadIdx.x;
    const int b = blockIdx.x;
    if (b < 16) min_enc[b * 256 + t] = 0xFFFFFFFFu;

    const bool is_z = b < 256;
    const int rb = b & 255;
    const float* src = (is_z ? z : e) + (size_t)rb * 16 * ZDIM;
    uint8_t* dst = (is_z ? zb : eb) + (size_t)rb * 16384;   // 16 KB seg
    const int w = t >> 6, lane = t & 63;

    // Phase 1: coalesced loads, fp32 row sums (R8-proven reduction),
    // pack 4 floats -> 4 fp8 into one dword in LDS.
    #pragma unroll
    for (int it = 0; it < 16; it++) {
        float4 v = reinterpret_cast<const float4*>(src + (size_t)it * ZDIM)[t];
        int pk = 0;
        pk = __builtin_amdgcn_cvt_pk_fp8_f32(v.x, v.y, pk, false);
        pk = __builtin_amdgcn_cvt_pk_fp8_f32(v.z, v.w, pk, true);
        *reinterpret_cast<int*>(&tile[it * PREP_PITCH_B + t * 4]) = pk;
        float s = v.x * v.x + v.y * v.y + v.z * v.z + v.w * v.w;
        #pragma unroll
        for (int off = 1; off < 64; off <<= 1) s += __shfl_xor(s, off, 64);
        if (lane == 0) redbuf[it * 4 + w] = s;
    }
    __syncthreads();

    // Phase 2: transpose-store to tiled global (chunk c -> dst + c*8, linear).
    #pragma unroll
    for (int it2 = 0; it2 < 8; it2++) {
        const int c = it2 * 256 + t;          // 0..2047
        const int kg = c >> 4, r16 = c & 15;
        const unsigned long long val = *reinterpret_cast<const unsigned long long*>(
            &tile[r16 * PREP_PITCH_B + kg * 8]);
        *reinterpret_cast<unsigned long long*>(&dst[(size_t)c * 8]) = val;
    }
    if (t < 16) {
        float sq = redbuf[t * 4] + redbuf[t * 4 + 1] +
                   redbuf[t * 4 + 2] + redbuf[t * 4 + 3];
        const int row = rb * 16 + t;
        if (is_z) zsq[row] = sq; else esq[row] = sq;
    }
}

// ---------------------------------------------------------------------------
// gemm_min (fp8 MX, 4x1 wave grid): R3 showed MFMA-halving bought nothing ->
// not MFMA-bound; bound by B global traffic + latency hiding. Changes:
// (1) Wave mapping 2x2 -> 4x1: each wave = ALL 128 rows x one 32-col stripe.
//     B fragments fully distinct across waves (B global traffic halves to
//     128 MB total); A LDS reads double (cheap, LDS far under BW).
// (2) VGPR min-demand: acc 8x2=64 + 2 live B-frags 16 + A-frag 8 + addr ~25
//     = ~113 < 128 -> __launch_bounds__(256,4) fits WITHOUT spill (R2's
//     forced spill was min-demand 134 > 128). Watch WRITE_SIZE for spill.
// (3) Bijective XCD swizzle: lin=by*32+bx; sw=(lin&7)*128+(lin>>3);
//     sbx=sw>>5, sby=sw&31 -> XCD x owns sbx in [4x,4x+4): its 4 B panels
//     (512 KB) stay L2-resident (latency-sensitive B loads hit L2); A
//     streams via latency-tolerant DMA. 1024 % 8 == 0 -> bijective.
// (4) Epilogue: wave-local col-min (no colmin LDS, no extra barrier).
// Pipeline unchanged: single-barrier double-buffered A-DMA, K-stage=128,
// 8 stages, mfma_scale_f32_16x16x128_f8f6f4 with unit scales (0x7F).
// ---------------------------------------------------------------------------
__global__ __launch_bounds__(256, 4) void gemm_min_kernel(
    const uint8_t* __restrict__ zb, const uint8_t* __restrict__ eb,
    const float* __restrict__ zsq, unsigned* __restrict__ min_enc) {
    __shared__ __align__(16) uint8_t As[32768];  // 2 x 16 KB (8 segs x 2 KB)
    __shared__ float zsq_s[128];

    const int t = threadIdx.x;        // 0..255
    const int lin = blockIdx.y * 32 + blockIdx.x;
    const int sw  = (lin & 7) * 128 + (lin >> 3);
    const int sbx = sw >> 5;          // code (col) block, XCD-contiguous
    const int sby = sw & 31;          // point (row) block
    const int lane = t & 63;
    const int w = t >> 6;             // 0..3: wave = 32-col stripe
    const int lrow = lane & 15;       // r16: frag row/col index
    const int q = lane >> 4;          // 0..3: k-group within fragment

    if (t < 128) zsq_s[t] = zsq[sby * 128 + t];

    f32x4 acc[8][2];
    #pragma unroll
    for (int i = 0; i < 8; i++) {
        acc[i][0] = (f32x4){0.f, 0.f, 0.f, 0.f};
        acc[i][1] = (f32x4){0.f, 0.f, 0.f, 0.f};
    }

    // A staging: per stage 16 KB (8 segs x 2 KB run). Instr j (0..3) = 4 KB:
    // waves {0,1} -> seg 2j, waves {2,3} -> seg 2j+1; inner = (t&127)*16.
    const int seg_half = t >> 7;            // 0..1
    const int inner = (t & 127) * 16;       // byte offset in 2 KB run
    const size_t a_seg0 = (size_t)(sby * 8) * 16384;

    // Per-lane fragment byte offset within one seg's 2 KB K-stage window:
    // lane l needs k = q*32 + p*8 + ke  ->  bytes at q*512 + p*128 + r16*8.
    const int frag_off = q * 512 + lrow * 8;
    // Wave w's two B segs: sbx*8 + w*2 {+0,+1}.
    const uint8_t* b_frag =
        eb + (size_t)(sbx * 8 + w * 2) * 16384 + frag_off;

#define DMA_STAGE(st_)                                                        \
    {                                                                         \
        const int buf_ = ((st_) & 1) * 16384;                                 \
        const int koff_ = (st_) * 2048;  /* byte offset within seg */         \
        _Pragma("unroll")                                                     \
        for (int j = 0; j < 4; j++) {                                         \
            const uint8_t* ga = zb + a_seg0 +                                 \
                (size_t)(j * 2 + seg_half) * 16384 + koff_ + inner;           \
            __builtin_amdgcn_global_load_lds(                                 \
                (const __attribute__((address_space(1))) void*)ga,            \
                (__attribute__((address_space(3))) void*)(As + buf_ +         \
                    (j * 2 + seg_half) * 2048 + inner), 16, 0, 0);            \
        }                                                                     \
    }

    // Assemble i32x8 fragment from 4x 8B loads (constant-index inserts only).
#define LOAD_FRAG(dst_, base_)                                                \
    {                                                                         \
        const int2 d0_ = *(const int2*)((base_));                             \
        const int2 d1_ = *(const int2*)((base_) + 128);                       \
        const int2 d2_ = *(const int2*)((base_) + 256);                       \
        const int2 d3_ = *(const int2*)((base_) + 384);                       \
        dst_[0] = d0_.x; dst_[1] = d0_.y;                                     \
        dst_[2] = d1_.x; dst_[3] = d1_.y;                                     \
        dst_[4] = d2_.x; dst_[5] = d2_.y;                                     \
        dst_[6] = d3_.x; dst_[7] = d3_.y;                                     \
    }

#define MXMFMA(a_, b_, c_)                                                    \
    __builtin_amdgcn_mfma_scale_f32_16x16x128_f8f6f4(                         \
        (a_), (b_), (c_), 0, 0, 0, 0x7F7F7F7F, 0, 0x7F7F7F7F)

    DMA_STAGE(0);
    for (int st = 0; st < 8; st++) {
        __syncthreads();                 // drains DMA(st)
        if (st < 7) DMA_STAGE(st + 1);   // overlaps with compute(st)
        const int buf = (st & 1) * 16384;
        const int koff = st * 2048;

        // Two B fragments (K=128), distinct per wave, live across am loop.
        i32x8 bf0, bf1;
        LOAD_FRAG(bf0, b_frag + koff);
        LOAD_FRAG(bf1, b_frag + 16384 + koff);

        // Stream A row-fragments (all 128 rows); 2 MX MFMAs each.
        #pragma unroll
        for (int am = 0; am < 8; am++) {
            i32x8 af;
            LOAD_FRAG(af, As + buf + am * 2048 + frag_off);
            acc[am][0] = MXMFMA(af, bf0, acc[am][0]);
            acc[am][1] = MXMFMA(af, bf1, acc[am][1]);
        }
    }
#undef DMA_STAGE
#undef LOAD_FRAG
#undef MXMFMA

    // Epilogue: wave-local column min (cols complete within wave).
    // C/D 16x16 layout: col = lane&15, row = q*4 + reg.
    #pragma unroll
    for (int an = 0; an < 2; an++) {
        float v = 3.4e38f;
        #pragma unroll
        for (int am = 0; am < 8; am++) {
            const int rbase = am * 16 + q * 4;
            f32x4 c = acc[am][an];
            v = fminf(v, zsq_s[rbase + 0] - 2.f * c[0]);
            v = fminf(v, zsq_s[rbase + 1] - 2.f * c[1]);
            v = fminf(v, zsq_s[rbase + 2] - 2.f * c[2]);
            v = fminf(v, zsq_s[rbase + 3] - 2.f * c[3]);
        }
        v = fminf(v, __shfl_xor(v, 16, 64));
        v = fminf(v, __shfl_xor(v, 32, 64));
        if (q == 0)
            atomicMin(&min_enc[sbx * 128 + w * 32 + an * 16 + lrow],
                      enc_f32(v));
    }
}

// ---------------------------------------------------------------------------
// finalize: mean_j (dec(min_enc[j]) + esq[j]) -> single fp32 scalar.
// ---------------------------------------------------------------------------
__global__ __launch_bounds__(256) void finalize_kernel(
    const unsigned* __restrict__ min_enc, const float* __restrict__ esq,
    float* __restrict__ out) {
    const int t = threadIdx.x;
    float s = 0.f;
    #pragma unroll
    for (int i = 0; i < M_CODES / 256; i++) {
        const int j = i * 256 + t;
        s += dec_f32(min_enc[j]) + esq[j];
    }
    #pragma unroll
    for (int off = 1; off < 64; off <<= 1) s += __shfl_xor(s, off, 64);
    __shared__ float red[4];
    if ((t & 63) == 0) red[t >> 6] = s;
    __syncthreads();
    if (t == 0) out[0] = (red[0] + red[1] + red[2] + red[3]) * (1.f / M_CODES);
}

extern "C" void kernel_launch(void* const* d_in, const int* in_sizes, int n_in,
                              void* d_out, int out_size, void* d_ws, size_t ws_size,
                              hipStream_t stream) {
    (void)in_sizes; (void)n_in; (void)out_size; (void)ws_size;
    const float* z = (const float*)d_in[0];
    const float* e = (const float*)d_in[1];
    char* ws = (char*)d_ws;
    uint8_t* zb = (uint8_t*)ws;                                          // 4 MB
    uint8_t* eb = (uint8_t*)(ws + ((size_t)4 << 20));                    // 4 MB
    float* zsq = (float*)(ws + ((size_t)8 << 20));                       // 16 KB
    float* esq = (float*)(ws + ((size_t)8 << 20) + 16384);               // 16 KB
    unsigned* min_enc = (unsigned*)(ws + ((size_t)8 << 20) + 32768);     // 16 KB

    prep_kernel<<<dim3(512), dim3(256), 0, stream>>>(
        z, e, zb, eb, zsq, esq, min_enc);
    gemm_min_kernel<<<dim3(32, 32), dim3(256), 0, stream>>>(
        zb, eb, zsq, min_enc);
    finalize_kernel<<<dim3(1), dim3(256), 0, stream>>>(min_enc, esq, (float*)d_out);
}

// Round 5
// 106.775 us; speedup vs baseline: 1.1363x; 1.1363x over previous
//
#include <hip/hip_runtime.h>
#include <hip/hip_bf16.h>
#include <stdint.h>

#define N_PTS   4096
#define M_CODES 4096
#define ZDIM    1024
// fp8 tiled layout: elem (r,k) at seg(rb)*16384 + kg*128 + r16*8 + ke  (BYTES)
//   rb=r>>4, r16=r&15, kg=k>>3, ke=k&7. Chunk (rb,kg) = 16 rows x 8 k = 128 B.
//   Seg = 16 rows x 1024 k x 1 B = 16 KB.

typedef __attribute__((ext_vector_type(4))) float f32x4;

__device__ __forceinline__ unsigned enc_f32(float f) {
    unsigned u = __float_as_uint(f);
    return (u & 0x80000000u) ? ~u : (u | 0x80000000u);
}
__device__ __forceinline__ float dec_f32(unsigned e) {
    unsigned u = (e & 0x80000000u) ? (e ^ 0x80000000u) : ~e;
    return __uint_as_float(u);
}

// ---------------------------------------------------------------------------
// prep: fp32 -> fp8 e4m3 (OCP) + tiled layout + row sum-of-squares (fp32,
// pre-quantization — error enters as 2(e.dz+z.de), sigma~2 << 35.5 threshold).
// One block = 16 rows. grid 512 (256 z + 256 e).
// ---------------------------------------------------------------------------
#define PREP_PITCH_B 1040   // bytes per LDS row: 1024 + 16 pad
__global__ __launch_bounds__(256) void prep_kernel(
    const float* __restrict__ z, const float* __restrict__ e,
    uint8_t* __restrict__ zb, uint8_t* __restrict__ eb,
    float* __restrict__ zsq, float* __restrict__ esq,
    unsigned* __restrict__ min_enc) {
    __shared__ uint8_t tile[16 * PREP_PITCH_B];   // ~16.6 KB
    __shared__ float redbuf[16 * 4];

    const int t = threadIdx.x;
    const int b = blockIdx.x;
    if (b < 16) min_enc[b * 256 + t] = 0xFFFFFFFFu;

    const bool is_z = b < 256;
    const int rb = b & 255;
    const float* src = (is_z ? z : e) + (size_t)rb * 16 * ZDIM;
    uint8_t* dst = (is_z ? zb : eb) + (size_t)rb * 16384;   // 16 KB seg
    const int w = t >> 6, lane = t & 63;

    // Phase 1: coalesced loads, fp32 row sums (R8-proven reduction),
    // pack 4 floats -> 4 fp8 into one dword in LDS.
    #pragma unroll
    for (int it = 0; it < 16; it++) {
        float4 v = reinterpret_cast<const float4*>(src + (size_t)it * ZDIM)[t];
        int pk = 0;
        pk = __builtin_amdgcn_cvt_pk_fp8_f32(v.x, v.y, pk, false);
        pk = __builtin_amdgcn_cvt_pk_fp8_f32(v.z, v.w, pk, true);
        *reinterpret_cast<int*>(&tile[it * PREP_PITCH_B + t * 4]) = pk;
        float s = v.x * v.x + v.y * v.y + v.z * v.z + v.w * v.w;
        #pragma unroll
        for (int off = 1; off < 64; off <<= 1) s += __shfl_xor(s, off, 64);
        if (lane == 0) redbuf[it * 4 + w] = s;
    }
    __syncthreads();

    // Phase 2: transpose-store to tiled global (chunk c -> dst + c*8, linear).
    #pragma unroll
    for (int it2 = 0; it2 < 8; it2++) {
        const int c = it2 * 256 + t;          // 0..2047
        const int kg = c >> 4, r16 = c & 15;
        const unsigned long long val = *reinterpret_cast<const unsigned long long*>(
            &tile[r16 * PREP_PITCH_B + kg * 8]);
        *reinterpret_cast<unsigned long long*>(&dst[(size_t)c * 8]) = val;
    }
    if (t < 16) {
        float sq = redbuf[t * 4] + redbuf[t * 4 + 1] +
                   redbuf[t * 4 + 2] + redbuf[t * 4 + 3];
        const int row = rb * 16 + t;
        if (is_z) zsq[row] = sq; else esq[row] = sq;
    }
}

// ---------------------------------------------------------------------------
// gemm_min: R0 champion base (16x16x32 fp8, 2x2 waves, (256,4)) with the
// structural stall removed (T3+T4 minimum form). R3/R4 lesson: MFMA-rate and
// traffic changes are invisible because __syncthreads() drains vmcnt(0)
// every stage (m233: stage+drain+barrier ~72% of critical path). Changes:
//   * K-stage 128 -> 64: 16 stages, 8 KB A per stage.
//   * TRIPLE-buffered LDS (3 x 8 KB), DMA prefetch depth 2: DMA(st+2)
//     issued during compute(st).
//   * Raw s_barrier + counted `s_waitcnt vmcnt(2)` at stage boundaries —
//     DMA(st+2) stays in flight ACROSS the barrier (never drain to 0
//     mid-loop; m218: counted-vs-drain0 is the whole T3 gain).
//   * B loads issued BEFORE DMA(st+2) in program order (sched_barrier(0)
//     pin): compiler's B-use waits become vmcnt(2), which (FIFO vmcnt
//     semantics) also proves DMA(st+1) retired before each barrier.
// Correctness: stage st reads buf st%3; DMA(st+2) writes (st+2)%3 — never
// the read or next-read buffer; WAR on (st+2)%3 (= buf of st-1) is fenced
// by the st-1 boundary barrier. VGPR: acc 64 + B 16 + A 8 + addr ~20 ~= 108
// < 128 -> no spill at (256,4). Epilogue unchanged (proven).
// ---------------------------------------------------------------------------
__global__ __launch_bounds__(256, 4) void gemm_min_kernel(
    const uint8_t* __restrict__ zb, const uint8_t* __restrict__ eb,
    const float* __restrict__ zsq, unsigned* __restrict__ min_enc) {
    __shared__ __align__(16) uint8_t As[3 * 8192];   // 3 bufs x (8 segs x 1 KB)
    __shared__ float zsq_s[128];
    __shared__ float colmin[2][128];

    const int t = threadIdx.x;        // 0..255
    const int bx = blockIdx.x;        // code (col) block
    const int by = blockIdx.y;        // point (row) block
    const int lane = t & 63;
    const int w = t >> 6;             // 0..3
    const int wm = w >> 1, wn = w & 1;
    const int lrow = lane & 15;
    const int q = lane >> 4;

    if (t < 128) zsq_s[t] = zsq[by * 128 + t];

    f32x4 acc[4][4];
    #pragma unroll
    for (int i = 0; i < 4; i++)
        #pragma unroll
        for (int j = 0; j < 4; j++) acc[i][j] = (f32x4){0.f, 0.f, 0.f, 0.f};

    const size_t a_seg0 = (size_t)(by * 8) * 16384;
    // B base: lane byte addr = lane*8 (lane-linear per fragment read).
    const uint8_t* b_base =
        eb + (size_t)(bx * 8 + wn * 4) * 16384 + lane * 8;

    // A staging per stage: 8 segs x 1 KB runs (seg's K-window st*1024).
    // 2 instrs x 256 thr x 16 B = 8 KB. Instr j: wave w -> seg j*4+w,
    // LDS dest = buf + seg*1024 + lane*16 (wave-uniform base + lane*16).
#define DMA_STAGE(st_)                                                        \
    {                                                                         \
        const int buf_ = ((st_) % 3) * 8192;                                  \
        _Pragma("unroll")                                                     \
        for (int j = 0; j < 2; j++) {                                         \
            const int seg_ = j * 4 + w;                                       \
            const uint8_t* ga = zb + a_seg0 + (size_t)seg_ * 16384 +          \
                (st_) * 1024 + lane * 16;                                     \
            __builtin_amdgcn_global_load_lds(                                 \
                (const __attribute__((address_space(1))) void*)ga,            \
                (__attribute__((address_space(3))) void*)(As + buf_ +         \
                    seg_ * 1024 + lane * 16), 16, 0, 0);                      \
        }                                                                     \
    }

    // Prologue: fill depth-2 pipe; wait own DMA(0) only (DMA(1) in flight).
    DMA_STAGE(0);
    DMA_STAGE(1);
    asm volatile("s_waitcnt vmcnt(2)" ::: "memory");
    __builtin_amdgcn_s_barrier();

    #pragma unroll
    for (int st = 0; st < 16; st++) {
        const int buf = (st % 3) * 8192;
        const int koff = st * 1024;

        // B loads for this stage (both K=32 slices) — FIRST, so every
        // compiler-inserted B-use wait is vmcnt(2), preserving the prefetch.
        long bb0_0 = *(const long*)(b_base + 0 * 16384 + koff);
        long bb0_1 = *(const long*)(b_base + 1 * 16384 + koff);
        long bb0_2 = *(const long*)(b_base + 2 * 16384 + koff);
        long bb0_3 = *(const long*)(b_base + 3 * 16384 + koff);
        long bb1_0 = *(const long*)(b_base + 0 * 16384 + koff + 512);
        long bb1_1 = *(const long*)(b_base + 1 * 16384 + koff + 512);
        long bb1_2 = *(const long*)(b_base + 2 * 16384 + koff + 512);
        long bb1_3 = *(const long*)(b_base + 3 * 16384 + koff + 512);
        __builtin_amdgcn_sched_barrier(0);   // pin B loads above DMA

        if (st < 14) DMA_STAGE(st + 2);      // depth-2 prefetch

        // Compute stage st from buf (two K=32 slices).
        #pragma unroll
        for (int sl = 0; sl < 2; sl++) {
            long a0 = *(const long*)(As + buf + (wm * 4 + 0) * 1024 +
                                     sl * 512 + lane * 8);
            long a1 = *(const long*)(As + buf + (wm * 4 + 1) * 1024 +
                                     sl * 512 + lane * 8);
            long a2 = *(const long*)(As + buf + (wm * 4 + 2) * 1024 +
                                     sl * 512 + lane * 8);
            long a3 = *(const long*)(As + buf + (wm * 4 + 3) * 1024 +
                                     sl * 512 + lane * 8);
            const long b0 = sl ? bb1_0 : bb0_0;
            const long b1 = sl ? bb1_1 : bb0_1;
            const long b2 = sl ? bb1_2 : bb0_2;
            const long b3 = sl ? bb1_3 : bb0_3;
            acc[0][0] = __builtin_amdgcn_mfma_f32_16x16x32_fp8_fp8(a0, b0, acc[0][0], 0, 0, 0);
            acc[0][1] = __builtin_amdgcn_mfma_f32_16x16x32_fp8_fp8(a0, b1, acc[0][1], 0, 0, 0);
            acc[0][2] = __builtin_amdgcn_mfma_f32_16x16x32_fp8_fp8(a0, b2, acc[0][2], 0, 0, 0);
            acc[0][3] = __builtin_amdgcn_mfma_f32_16x16x32_fp8_fp8(a0, b3, acc[0][3], 0, 0, 0);
            acc[1][0] = __builtin_amdgcn_mfma_f32_16x16x32_fp8_fp8(a1, b0, acc[1][0], 0, 0, 0);
            acc[1][1] = __builtin_amdgcn_mfma_f32_16x16x32_fp8_fp8(a1, b1, acc[1][1], 0, 0, 0);
            acc[1][2] = __builtin_amdgcn_mfma_f32_16x16x32_fp8_fp8(a1, b2, acc[1][2], 0, 0, 0);
            acc[1][3] = __builtin_amdgcn_mfma_f32_16x16x32_fp8_fp8(a1, b3, acc[1][3], 0, 0, 0);
            acc[2][0] = __builtin_amdgcn_mfma_f32_16x16x32_fp8_fp8(a2, b0, acc[2][0], 0, 0, 0);
            acc[2][1] = __builtin_amdgcn_mfma_f32_16x16x32_fp8_fp8(a2, b1, acc[2][1], 0, 0, 0);
            acc[2][2] = __builtin_amdgcn_mfma_f32_16x16x32_fp8_fp8(a2, b2, acc[2][2], 0, 0, 0);
            acc[2][3] = __builtin_amdgcn_mfma_f32_16x16x32_fp8_fp8(a2, b3, acc[2][3], 0, 0, 0);
            acc[3][0] = __builtin_amdgcn_mfma_f32_16x16x32_fp8_fp8(a3, b0, acc[3][0], 0, 0, 0);
            acc[3][1] = __builtin_amdgcn_mfma_f32_16x16x32_fp8_fp8(a3, b1, acc[3][1], 0, 0, 0);
            acc[3][2] = __builtin_amdgcn_mfma_f32_16x16x32_fp8_fp8(a3, b2, acc[3][2], 0, 0, 0);
            acc[3][3] = __builtin_amdgcn_mfma_f32_16x16x32_fp8_fp8(a3, b3, acc[3][3], 0, 0, 0);
        }

        // Stage boundary: counted wait (DMA(st+2) stays in flight), raw
        // barrier. st==14: drain DMA(15) fully (no DMA(16) exists).
        if (st < 15) {
            __builtin_amdgcn_sched_barrier(0);
            if (st < 14) {
                asm volatile("s_waitcnt vmcnt(2)" ::: "memory");
            } else {
                asm volatile("s_waitcnt vmcnt(0)" ::: "memory");
            }
            __builtin_amdgcn_s_barrier();
            __builtin_amdgcn_sched_barrier(0);
        }
    }
#undef DMA_STAGE

    __syncthreads();

    // Epilogue (proven; C/D layout shape-determined): row = q*4+r, col = lrow.
    #pragma unroll
    for (int an = 0; an < 4; an++) {
        float v = 3.4e38f;
        #pragma unroll
        for (int am = 0; am < 4; am++) {
            const int rbase = wm * 64 + am * 16 + q * 4;
            f32x4 c = acc[am][an];
            v = fminf(v, zsq_s[rbase + 0] - 2.f * c[0]);
            v = fminf(v, zsq_s[rbase + 1] - 2.f * c[1]);
            v = fminf(v, zsq_s[rbase + 2] - 2.f * c[2]);
            v = fminf(v, zsq_s[rbase + 3] - 2.f * c[3]);
        }
        v = fminf(v, __shfl_xor(v, 16, 64));
        v = fminf(v, __shfl_xor(v, 32, 64));
        if (q == 0) colmin[wm][wn * 64 + an * 16 + lrow] = v;
    }
    __syncthreads();
    if (t < 128) {
        const float m = fminf(colmin[0][t], colmin[1][t]);
        atomicMin(&min_enc[bx * 128 + t], enc_f32(m));
    }
}

// ---------------------------------------------------------------------------
// finalize: mean_j (dec(min_enc[j]) + esq[j]) -> single fp32 scalar.
// ---------------------------------------------------------------------------
__global__ __launch_bounds__(256) void finalize_kernel(
    const unsigned* __restrict__ min_enc, const float* __restrict__ esq,
    float* __restrict__ out) {
    const int t = threadIdx.x;
    float s = 0.f;
    #pragma unroll
    for (int i = 0; i < M_CODES / 256; i++) {
        const int j = i * 256 + t;
        s += dec_f32(min_enc[j]) + esq[j];
    }
    #pragma unroll
    for (int off = 1; off < 64; off <<= 1) s += __shfl_xor(s, off, 64);
    __shared__ float red[4];
    if ((t & 63) == 0) red[t >> 6] = s;
    __syncthreads();
    if (t == 0) out[0] = (red[0] + red[1] + red[2] + red[3]) * (1.f / M_CODES);
}

extern "C" void kernel_launch(void* const* d_in, const int* in_sizes, int n_in,
                              void* d_out, int out_size, void* d_ws, size_t ws_size,
                              hipStream_t stream) {
    (void)in_sizes; (void)n_in; (void)out_size; (void)ws_size;
    const float* z = (const float*)d_in[0];
    const float* e = (const float*)d_in[1];
    char* ws = (char*)d_ws;
    uint8_t* zb = (uint8_t*)ws;                                          // 4 MB
    uint8_t* eb = (uint8_t*)(ws + ((size_t)4 << 20));                    // 4 MB
    float* zsq = (float*)(ws + ((size_t)8 << 20));                       // 16 KB
    float* esq = (float*)(ws + ((size_t)8 << 20) + 16384);               // 16 KB
    unsigned* min_enc = (unsigned*)(ws + ((size_t)8 << 20) + 32768);     // 16 KB

    prep_kernel<<<dim3(512), dim3(256), 0, stream>>>(
        z, e, zb, eb, zsq, esq, min_enc);
    gemm_min_kernel<<<dim3(32, 32), dim3(256), 0, stream>>>(
        zb, eb, zsq, min_enc);
    finalize_kernel<<<dim3(1), dim3(256), 0, stream>>>(min_enc, esq, (float*)d_out);
}